// Round 3
// baseline (420.082 us; speedup 1.0000x reference)
//
#include <hip/hip_runtime.h>

#define BB 4
#define TT 2048
#define EE 4096
#define HH 128
#define MM (BB*TT)          // 8192
#define SCALE 0.015625f     // E^-0.5 = 1/64

typedef short short8 __attribute__((ext_vector_type(8)));
typedef float f32x4 __attribute__((ext_vector_type(4)));
typedef unsigned short ushort_t;
typedef unsigned int u32;

__device__ __forceinline__ unsigned short f2bf(float x) {
    unsigned int u = __float_as_uint(x);
    u = (u + 0x7fffu + ((u >> 16) & 1u)) >> 16;   // RNE
    return (unsigned short)u;
}

// ---------------------------------------------------------------------------
// Kernel 1: convert Wq|Wk|Wv -> bf16 [3][128][4096]; Wq pre-scaled by 1/64.
// ---------------------------------------------------------------------------
__global__ __launch_bounds__(256) void wconv(
    const float* __restrict__ Wq, const float* __restrict__ Wk,
    const float* __restrict__ Wv, ushort_t* __restrict__ Wb)
{
    const int gid = blockIdx.x * 256 + threadIdx.x;
    const int which = gid >> 16;
    const int rem = gid & 65535;
    const float* W = (which == 0) ? Wq : (which == 1) ? Wk : Wv;
    const float sc = (which == 0) ? SCALE : 1.0f;
    const float4 f0 = *(const float4*)(W + (size_t)rem * 8);
    const float4 f1 = *(const float4*)(W + (size_t)rem * 8 + 4);
    short8 pk;
    pk[0] = (short)f2bf(f0.x * sc); pk[1] = (short)f2bf(f0.y * sc);
    pk[2] = (short)f2bf(f0.z * sc); pk[3] = (short)f2bf(f0.w * sc);
    pk[4] = (short)f2bf(f1.x * sc); pk[5] = (short)f2bf(f1.y * sc);
    pk[6] = (short)f2bf(f1.z * sc); pk[7] = (short)f2bf(f1.w * sc);
    *(short8*)(Wb + (size_t)which * 524288 + (size_t)rem * 8) = pk;
}

// ---------------------------------------------------------------------------
// Kernel 2 (v4): BARRIER-FREE, LDS-FREE MFMA projection.
// Each wave independently computes 32(M) x 128(N) over K-span 1024 (split-K 4).
// A (f32) loaded per-lane in MFMA fragment layout + cvt to bf16.
// B (bf16, L2-resident 1MB/widx) loaded per-lane as fragments, reused across
// both M-halves. 16 MFMA per k-step, zero __syncthreads, zero LDS.
// Grid (64, 3, 4) = 768 blocks = 3/CU; launch_bounds(256,3) -> <=170 VGPR.
// fp32 partials out (summed by projcomb).
// ---------------------------------------------------------------------------
#define KSPLIT 4
#define KSPAN  1024

__global__ __launch_bounds__(256, 3) void proj_mfma(
    const float* __restrict__ x, const float* __restrict__ pe,
    const ushort_t* __restrict__ Wb, float* __restrict__ Pp)
{
    const int mb   = blockIdx.x;     // 0..63  (128 rows per block)
    const int widx = blockIdx.y;     // 0:q 1:k 2:v
    const int sp   = blockIdx.z;     // 0..3 K-split
    const float* in = (widx == 1) ? pe : x;
    const ushort_t* W = Wb + (size_t)widx * (128 * EE);

    const int tid  = threadIdx.x;
    const int lane = tid & 63, wave = tid >> 6;
    const int fr = lane & 15, quad = lane >> 4;

    const int rb    = mb * 128 + wave * 32;   // this wave's 32 rows
    const int kbase = sp * KSPAN;

    f32x4 acc[2][8];
    #pragma unroll
    for (int m = 0; m < 2; m++)
        #pragma unroll
        for (int n = 0; n < 8; n++) acc[m][n] = (f32x4){0.f,0.f,0.f,0.f};

    // A fragment pointers: lane (fr,quad) holds A[row][quad*8 .. +7]
    const float* a0p = in + (size_t)(rb + fr) * EE + kbase + quad * 8;
    const float* a1p = in + (size_t)(rb + 16 + fr) * EE + kbase + quad * 8;
    // B fragment pointer: lane holds W[n*16+fr][quad*8 .. +7]
    const ushort_t* bp = W + (size_t)fr * EE + kbase + quad * 8;

    for (int kk = 0; kk < KSPAN; kk += 32) {
        // ---- loads (no barriers anywhere: compiler emits counted vmcnt) ----
        const float4 x00 = *(const float4*)(a0p + kk);
        const float4 x01 = *(const float4*)(a0p + kk + 4);
        const float4 x10 = *(const float4*)(a1p + kk);
        const float4 x11 = *(const float4*)(a1p + kk + 4);
        short8 bf[8];
        #pragma unroll
        for (int n = 0; n < 8; n++)
            bf[n] = *(const short8*)(bp + (size_t)n * 16 * EE + kk);

        // ---- cvt A fragments ----
        short8 af0, af1;
        af0[0]=(short)f2bf(x00.x); af0[1]=(short)f2bf(x00.y);
        af0[2]=(short)f2bf(x00.z); af0[3]=(short)f2bf(x00.w);
        af0[4]=(short)f2bf(x01.x); af0[5]=(short)f2bf(x01.y);
        af0[6]=(short)f2bf(x01.z); af0[7]=(short)f2bf(x01.w);
        af1[0]=(short)f2bf(x10.x); af1[1]=(short)f2bf(x10.y);
        af1[2]=(short)f2bf(x10.z); af1[3]=(short)f2bf(x10.w);
        af1[4]=(short)f2bf(x11.x); af1[5]=(short)f2bf(x11.y);
        af1[6]=(short)f2bf(x11.z); af1[7]=(short)f2bf(x11.w);

        // ---- 16 MFMAs ----
        #pragma unroll
        for (int n = 0; n < 8; n++) {
            acc[0][n] = __builtin_amdgcn_mfma_f32_16x16x32_bf16(af0, bf[n], acc[0][n], 0, 0, 0);
            acc[1][n] = __builtin_amdgcn_mfma_f32_16x16x32_bf16(af1, bf[n], acc[1][n], 0, 0, 0);
        }
    }

    // ---- epilogue: fp32 partial [widx*4+sp][M][H]; C: col=fr, row=quad*4+r ----
    float* P = Pp + ((size_t)(widx * KSPLIT + sp) * MM + rb) * HH;
    #pragma unroll
    for (int m = 0; m < 2; m++)
        #pragma unroll
        for (int n = 0; n < 8; n++)
            #pragma unroll
            for (int r = 0; r < 4; r++)
                P[(size_t)(m * 16 + quad * 4 + r) * HH + n * 16 + fr] = acc[m][n][r];
}

// ---------------------------------------------------------------------------
// Kernel 2b: sum 4 K-split partials -> bf16 q,k and transposed vt.
// Grid (128, 3): 64 M-rows x 128 H per block.
// ---------------------------------------------------------------------------
__global__ __launch_bounds__(256) void projcomb(
    const float* __restrict__ Pp,
    ushort_t* __restrict__ qo, ushort_t* __restrict__ ko_,
    ushort_t* __restrict__ vto)
{
    const int mb   = blockIdx.x;     // 0..127
    const int widx = blockIdx.y;
    const int tid  = threadIdx.x;
    const int m0 = mb * 64;
    const int r_ = tid >> 2;             // 0..63
    const int h0 = (tid & 3) * 32;       // 0,32,64,96

    __shared__ ushort_t T[128 * 72];

    const float* base = Pp + ((size_t)widx * KSPLIT * MM + m0 + r_) * HH + h0;
    float accv[32];
    #pragma unroll
    for (int j = 0; j < 8; j++) {
        float4 a = *(const float4*)(base + j * 4);
        accv[4*j+0] = a.x; accv[4*j+1] = a.y; accv[4*j+2] = a.z; accv[4*j+3] = a.w;
    }
    #pragma unroll
    for (int s = 1; s < KSPLIT; s++) {
        const float* bs = base + (size_t)s * MM * HH;
        #pragma unroll
        for (int j = 0; j < 8; j++) {
            float4 a = *(const float4*)(bs + j * 4);
            accv[4*j+0] += a.x; accv[4*j+1] += a.y;
            accv[4*j+2] += a.z; accv[4*j+3] += a.w;
        }
    }

    if (widx < 2) {
        ushort_t* out = (widx == 0) ? qo : ko_;
        #pragma unroll
        for (int j = 0; j < 4; j++) {
            short8 s_;
            #pragma unroll
            for (int e = 0; e < 8; e++) s_[e] = (short)f2bf(accv[j*8 + e]);
            *(short8*)&out[(size_t)(m0 + r_) * HH + h0 + j * 8] = s_;
        }
    } else {
        // transpose 64m x 128h tile via LDS -> vt[h][m]
        #pragma unroll
        for (int e = 0; e < 32; e++)
            T[(h0 + e) * 72 + r_] = f2bf(accv[e]);
        __syncthreads();
        const int h = tid >> 1, ms = (tid & 1) * 32;
        #pragma unroll
        for (int j = 0; j < 4; j++)
            *(short8*)&vto[(size_t)h * MM + m0 + ms + j * 8]
                = *(short8*)&T[h * 72 + ms + j * 8];
    }
}

// ---------------------------------------------------------------------------
// Kernel 3: MFMA flash attention partials (no-max streaming softmax, split-2).
// Qtile=32, Kchunk=64. Grid (64, 2, BB). bf16 q,k,vt in; fp32 partials out.
// ---------------------------------------------------------------------------
__global__ __launch_bounds__(256) void attn_mfma(
    const ushort_t* __restrict__ qb, const ushort_t* __restrict__ kbf,
    const ushort_t* __restrict__ vtb,
    float* __restrict__ OP, float* __restrict__ LP)
{
    const int b = blockIdx.z;
    const int s = blockIdx.y;
    const int t = 63 - (int)blockIdx.x;       // heavy tiles first
    const int tid  = threadIdx.x;
    const int lane = tid & 63, wave = tid >> 6;
    const int fr = lane & 15, quad = lane >> 4, ko = quad * 8;

    const int q0 = t * 32;
    const int C  = (t + 2) >> 1;              // chunks of 64 keys
    const int cs = (C + 1) >> 1;
    const int c0 = s ? cs : 0;
    const int c1 = s ? C  : cs;

    __shared__ __align__(16) ushort_t Qs[32 * 136];
    __shared__ __align__(16) ushort_t Ks[64 * 136];
    __shared__ __align__(16) ushort_t Vt[128 * 72];
    __shared__ __align__(16) ushort_t Ps[32 * 72];
    __shared__ float lred[2][32];

    // load Q tile (32 rows x 16 segs)
    for (int f = tid; f < 512; f += 256) {
        const int row = f >> 4, sg = f & 15;
        *(short8*)&Qs[row * 136 + sg * 8] =
            *(const short8*)(qb + (size_t)(b * TT + q0 + row) * HH + sg * 8);
    }

    const int rhS = (wave & 1) * 16, cqS = (wave >> 1) * 32;   // S partition
    const int rhO = (wave & 1) * 16, chO = (wave >> 1) * 64;   // O partition

    f32x4 oacc[4];
    #pragma unroll
    for (int i = 0; i < 4; i++) oacc[i] = (f32x4){0.f,0.f,0.f,0.f};
    float lacc[4] = {0.f, 0.f, 0.f, 0.f};

    for (int c = c0; c < c1; c++) {
        const int kb_ = c * 64;
        // stage K (64 x 16 segs)
        for (int f = tid; f < 1024; f += 256) {
            const int row = f >> 4, sg = f & 15;
            *(short8*)&Ks[row * 136 + sg * 8] =
                *(const short8*)(kbf + (size_t)(b * TT + kb_ + row) * HH + sg * 8);
        }
        // stage Vt (128 x 8 segs)
        for (int f = tid; f < 1024; f += 256) {
            const int h = f >> 3, sg = f & 7;
            *(short8*)&Vt[h * 72 + sg * 8] =
                *(const short8*)(vtb + (size_t)h * MM + b * TT + kb_ + sg * 8);
        }
        __syncthreads();

        // ---- QK: S[32x64], this wave: rows rhS..+16, cols cqS..+32 ----
        f32x4 sacc[2];
        sacc[0] = (f32x4){0.f,0.f,0.f,0.f};
        sacc[1] = (f32x4){0.f,0.f,0.f,0.f};
        #pragma unroll
        for (int kk = 0; kk < 128; kk += 32) {
            const short8 af = *(short8*)&Qs[(rhS + fr) * 136 + kk + ko];
            const short8 b0 = *(short8*)&Ks[(cqS + fr) * 136 + kk + ko];
            const short8 b1 = *(short8*)&Ks[(cqS + 16 + fr) * 136 + kk + ko];
            sacc[0] = __builtin_amdgcn_mfma_f32_16x16x32_bf16(af, b0, sacc[0], 0, 0, 0);
            sacc[1] = __builtin_amdgcn_mfma_f32_16x16x32_bf16(af, b1, sacc[1], 0, 0, 0);
        }

        // ---- epilogue: mask + exp -> Ps (bf16), accumulate l ----
        #pragma unroll
        for (int tl = 0; tl < 2; tl++)
            #pragma unroll
            for (int r = 0; r < 4; r++) {
                const int row = rhS + quad * 4 + r;
                const int col = cqS + tl * 16 + fr;
                const float p = ((kb_ + col) <= (q0 + row)) ? __expf(sacc[tl][r]) : 0.f;
                lacc[r] += p;
                Ps[row * 72 + col] = f2bf(p);
            }
        __syncthreads();

        // ---- PV: O[32x128] += P[32x64] * V; wave: rows rhO, cols chO..+64 ----
        #pragma unroll
        for (int ks = 0; ks < 64; ks += 32) {
            const short8 af = *(short8*)&Ps[(rhO + fr) * 72 + ks + ko];
            #pragma unroll
            for (int tl = 0; tl < 4; tl++) {
                const short8 bf_ = *(short8*)&Vt[(chO + tl * 16 + fr) * 72 + ks + ko];
                oacc[tl] = __builtin_amdgcn_mfma_f32_16x16x32_bf16(af, bf_, oacc[tl], 0, 0, 0);
            }
        }
        __syncthreads();
    }

    // ---- l reduction: sum over the 16 fr-lanes, combine col-halves ----
    #pragma unroll
    for (int r = 0; r < 4; r++) {
        float v = lacc[r];
        #pragma unroll
        for (int m = 1; m < 16; m <<= 1) v += __shfl_xor(v, m);
        lacc[r] = v;
    }
    if (fr == 0) {
        #pragma unroll
        for (int r = 0; r < 4; r++)
            lred[wave >> 1][rhS + quad * 4 + r] = lacc[r];
    }
    __syncthreads();
    const int pbase = ((b * 64 + t) * 2 + s);
    if (tid < 32) LP[(size_t)pbase * 32 + tid] = lred[0][tid] + lred[1][tid];

    // ---- write O partial ----
    #pragma unroll
    for (int tl = 0; tl < 4; tl++)
        #pragma unroll
        for (int r = 0; r < 4; r++) {
            const int row = rhO + quad * 4 + r;
            const int col = chO + tl * 16 + fr;
            OP[(size_t)pbase * 4096 + row * 128 + col] = oacc[tl][r];
        }
}

// ---------------------------------------------------------------------------
// Kernel 4: combine: out = (O0+O1)/(l0+l1). 262144 float4.
// ---------------------------------------------------------------------------
__global__ __launch_bounds__(256) void combine(
    const float* __restrict__ OP, const float* __restrict__ LP,
    float* __restrict__ out)
{
    const int gid = blockIdx.x * 256 + threadIdx.x;
    const int b = gid >> 16;
    const int rem = gid & 65535;
    const int qrow = rem >> 5, h4 = rem & 31;
    const int t = qrow >> 5, r = qrow & 31;
    const int base = (b * 64 + t) * 2;
    const float l = LP[(size_t)base * 32 + r] + LP[(size_t)(base + 1) * 32 + r];
    const float inv = 1.f / l;
    const float4 a = ((const float4*)OP)[(size_t)base * 1024 + r * 32 + h4];
    const float4 c = ((const float4*)OP)[(size_t)(base + 1) * 1024 + r * 32 + h4];
    float4 res;
    res.x = (a.x + c.x) * inv; res.y = (a.y + c.y) * inv;
    res.z = (a.z + c.z) * inv; res.w = (a.w + c.w) * inv;
    ((float4*)out)[gid] = res;
}

// ---------------------------------------------------------------------------
extern "C" void kernel_launch(void* const* d_in, const int* in_sizes, int n_in,
                              void* d_out, int out_size, void* d_ws, size_t ws_size,
                              hipStream_t stream) {
    const float* x  = (const float*)d_in[0];
    const float* pe = (const float*)d_in[1];
    const float* Wq = (const float*)d_in[2];
    const float* Wk = (const float*)d_in[3];
    const float* Wv = (const float*)d_in[4];
    float* out = (float*)d_out;

    ushort_t* qb  = (ushort_t*)d_ws;                 // [MM][HH] bf16   (2 MB)
    ushort_t* kbf = qb  + (size_t)MM * HH;           // [MM][HH] bf16   (2 MB)
    ushort_t* vtb = kbf + (size_t)MM * HH;           // [HH][MM] bf16   (2 MB)
    ushort_t* Wb  = vtb + (size_t)MM * HH;           // [3][128][4096]  (3 MB)
    float* Pp = (float*)(Wb + (size_t)3 * 128 * 4096); // [12][MM][HH] f32 (48 MB)
    float* OP = Pp;                                  // overlap: Pp dead before OP
    float* LP = OP + (size_t)512 * 4096;             // [512][32] f32

    wconv    <<<768, 256, 0, stream>>>(Wq, Wk, Wv, Wb);
    proj_mfma<<<dim3(64, 3, KSPLIT), 256, 0, stream>>>(x, pe, Wb, Pp);
    projcomb <<<dim3(128, 3), 256, 0, stream>>>(Pp, qb, kbf, vtb);
    attn_mfma<<<dim3(64, 2, BB), 256, 0, stream>>>(qb, kbf, vtb, OP, LP);
    combine  <<<1024, 256, 0, stream>>>(OP, LP, out);
}

// Round 4
// 376.480 us; speedup vs baseline: 1.1158x; 1.1158x over previous
//
#include <hip/hip_runtime.h>

#define BB 4
#define TT 2048
#define EE 4096
#define HH 128
#define MM (BB*TT)          // 8192
#define SCALE 0.015625f     // E^-0.5 = 1/64

typedef short short8 __attribute__((ext_vector_type(8)));
typedef float f32x4 __attribute__((ext_vector_type(4)));
typedef unsigned short ushort_t;
typedef unsigned int u32;

__device__ __forceinline__ unsigned short f2bf(float x) {
    unsigned int u = __float_as_uint(x);
    u = (u + 0x7fffu + ((u >> 16) & 1u)) >> 16;   // RNE
    return (unsigned short)u;
}

__device__ __forceinline__ void gl_lds16(const void* g, void* l) {
    __builtin_amdgcn_global_load_lds(
        (const __attribute__((address_space(1))) u32*)g,
        (__attribute__((address_space(3))) u32*)l, 16, 0, 0);
}

// ---------------------------------------------------------------------------
// Kernel 1: convert Wq|Wk|Wv -> bf16 [3][128][4096]; Wq pre-scaled by 1/64.
// ---------------------------------------------------------------------------
__global__ __launch_bounds__(256) void wconv(
    const float* __restrict__ Wq, const float* __restrict__ Wk,
    const float* __restrict__ Wv, ushort_t* __restrict__ Wb)
{
    const int gid = blockIdx.x * 256 + threadIdx.x;
    const int which = gid >> 16;
    const int rem = gid & 65535;
    const float* W = (which == 0) ? Wq : (which == 1) ? Wk : Wv;
    const float sc = (which == 0) ? SCALE : 1.0f;
    const float4 f0 = *(const float4*)(W + (size_t)rem * 8);
    const float4 f1 = *(const float4*)(W + (size_t)rem * 8 + 4);
    short8 pk;
    pk[0] = (short)f2bf(f0.x * sc); pk[1] = (short)f2bf(f0.y * sc);
    pk[2] = (short)f2bf(f0.z * sc); pk[3] = (short)f2bf(f0.w * sc);
    pk[4] = (short)f2bf(f1.x * sc); pk[5] = (short)f2bf(f1.y * sc);
    pk[6] = (short)f2bf(f1.z * sc); pk[7] = (short)f2bf(f1.w * sc);
    *(short8*)(Wb + (size_t)which * 524288 + (size_t)rem * 8) = pk;
}

// ---------------------------------------------------------------------------
// Kernel 2 (v5): all-coalesced gl_lds staging, no scattered VMEM in hot loop.
// Tile 128(M) x 128(N), BK=32, split-K=4. Grid (64,3,4)=768 blocks = 3/CU.
// A staged as RAW F32 via global_load_lds (full-line coalesced: 8 rows x 128B
// per wave-instr); cvt f32->bf16 at fragment-read. B (bf16) via gl_lds
// (16 rows x 64B full lines). XOR source-swizzle + swizzled ds_read (T2
// both-sides): A swz ^((row&7)<<4) -> conflict-free; B ^((row&3)<<4) -> 4-way.
// One __syncthreads per K-step, stage(t+1) issued before compute(t).
// LDS 48KB -> 3 blocks/CU. fp32 partials out.
// ---------------------------------------------------------------------------
#define KSPLIT 4
#define KSPAN  1024
#define BK     32
#define NSTEPS (KSPAN / BK)   // 32

__global__ __launch_bounds__(256, 3) void proj_mfma(
    const float* __restrict__ x, const float* __restrict__ pe,
    const ushort_t* __restrict__ Wb, float* __restrict__ Pp)
{
    const int mb   = blockIdx.x;     // 0..63
    const int widx = blockIdx.y;     // 0:q 1:k 2:v
    const int sp   = blockIdx.z;     // 0..3
    const float* in = (widx == 1) ? pe : x;
    const ushort_t* W = Wb + (size_t)widx * (128 * EE);

    const int rb    = mb * 128;
    const int kbase = sp * KSPAN;

    const int tid  = threadIdx.x;
    const int lane = tid & 63, wave = tid >> 6;
    const int wr = wave & 1, wc = wave >> 1;
    const int fr = lane & 15, quad = lane >> 4;

    __shared__ __align__(16) float    As[2][128 * BK];   // 16KB x2 (f32!)
    __shared__ __align__(16) ushort_t Bs[2][128 * BK];   //  8KB x2

    f32x4 acc[4][4];
    #pragma unroll
    for (int m = 0; m < 4; m++)
        #pragma unroll
        for (int n = 0; n < 4; n++) acc[m][n] = (f32x4){0.f,0.f,0.f,0.f};

    // ---- A stage map: round j(0..3): LDS byte j*4096 + tid*16
    //      -> row = j*32 + (tid>>3), in-row byte w = (tid&7)*16.
    //      Global src col-byte = w ^ ((row&7)<<4)  (row&7 indep of j).
    const int a_row = tid >> 3;
    const int a_sw  = (((tid & 7) * 16) ^ ((a_row & 7) << 4)) >> 2;  // floats
    const float* a_src = in + (size_t)(rb + a_row) * EE + kbase + a_sw;

    // ---- B stage map: round r(0..1): LDS byte r*4096 + tid*16
    //      -> row = r*64 + (tid>>2), w = (tid&3)*16; src ^((row&3)<<4).
    const int b_row = tid >> 2;
    const int b_sw  = (((tid & 3) * 16) ^ ((b_row & 3) << 4)) >> 1;  // ushorts
    const ushort_t* b_src = W + (size_t)b_row * EE + kbase + b_sw;

#define STAGE(K0, BUF) do { \
    _Pragma("unroll") \
    for (int j_ = 0; j_ < 4; j_++) \
        gl_lds16(a_src + (size_t)j_ * 32 * EE + (K0), \
                 &As[BUF][j_ * 1024 + tid * 4]); \
    _Pragma("unroll") \
    for (int r_ = 0; r_ < 2; r_++) \
        gl_lds16(b_src + (size_t)r_ * 64 * EE + (K0), \
                 &Bs[BUF][r_ * 2048 + tid * 8]); \
} while (0)

    // ---- reader swizzle offsets (constant per thread) ----
    // A frag m: row = wr*64+m*16+fr; (row&7)==(fr&7). 32B = 2 x 16B chunks.
    const int ac0 = ((quad * 32)      ^ ((fr & 7) << 4)) >> 2;  // float idx
    const int ac1 = ((quad * 32 + 16) ^ ((fr & 7) << 4)) >> 2;
    // B frag n: row = wc*64+n*16+fr; (row&3)==(fr&3). one 16B chunk.
    const int bc0 = ((quad * 16)      ^ ((fr & 3) << 4)) >> 1;  // ushort idx

    // ---- prologue ----
    STAGE(0, 0);
    __syncthreads();

    // ---- main loop: one barrier per step ----
    for (int s = 0; s < NSTEPS; s++) {
        const int buf = s & 1;
        if (s + 1 < NSTEPS) STAGE((s + 1) * BK, buf ^ 1);

        short8 bfr[4];
        #pragma unroll
        for (int n = 0; n < 4; n++)
            bfr[n] = *(short8*)&Bs[buf][(wc * 64 + n * 16 + fr) * BK + bc0];

        short8 afr[4];
        #pragma unroll
        for (int m = 0; m < 4; m++) {
            const int arow = (wr * 64 + m * 16 + fr) * BK;
            const f32x4 c0 = *(f32x4*)&As[buf][arow + ac0];
            const f32x4 c1 = *(f32x4*)&As[buf][arow + ac1];
            short8 a_;
            a_[0]=(short)f2bf(c0[0]); a_[1]=(short)f2bf(c0[1]);
            a_[2]=(short)f2bf(c0[2]); a_[3]=(short)f2bf(c0[3]);
            a_[4]=(short)f2bf(c1[0]); a_[5]=(short)f2bf(c1[1]);
            a_[6]=(short)f2bf(c1[2]); a_[7]=(short)f2bf(c1[3]);
            afr[m] = a_;
        }

        #pragma unroll
        for (int m = 0; m < 4; m++)
            #pragma unroll
            for (int n = 0; n < 4; n++)
                acc[m][n] = __builtin_amdgcn_mfma_f32_16x16x32_bf16(
                    afr[m], bfr[n], acc[m][n], 0, 0, 0);

        __syncthreads();
    }
#undef STAGE

    // ---- epilogue: fp32 partial [widx*4+sp][M][H]; C: col=fr, row=quad*4+r ----
    float* P = Pp + ((size_t)(widx * KSPLIT + sp) * MM + rb) * HH;
    #pragma unroll
    for (int m = 0; m < 4; m++)
        #pragma unroll
        for (int n = 0; n < 4; n++)
            #pragma unroll
            for (int r = 0; r < 4; r++)
                P[(size_t)(wr * 64 + m * 16 + quad * 4 + r) * HH
                  + wc * 64 + n * 16 + fr] = acc[m][n][r];
}

// ---------------------------------------------------------------------------
// Kernel 2b: sum 4 K-split partials -> bf16 q,k and transposed vt.
// Grid (128, 3): 64 M-rows x 128 H per block.
// ---------------------------------------------------------------------------
__global__ __launch_bounds__(256) void projcomb(
    const float* __restrict__ Pp,
    ushort_t* __restrict__ qo, ushort_t* __restrict__ ko_,
    ushort_t* __restrict__ vto)
{
    const int mb   = blockIdx.x;     // 0..127
    const int widx = blockIdx.y;
    const int tid  = threadIdx.x;
    const int m0 = mb * 64;
    const int r_ = tid >> 2;             // 0..63
    const int h0 = (tid & 3) * 32;       // 0,32,64,96

    __shared__ ushort_t T[128 * 72];

    const float* base = Pp + ((size_t)widx * KSPLIT * MM + m0 + r_) * HH + h0;
    float accv[32];
    #pragma unroll
    for (int j = 0; j < 8; j++) {
        float4 a = *(const float4*)(base + j * 4);
        accv[4*j+0] = a.x; accv[4*j+1] = a.y; accv[4*j+2] = a.z; accv[4*j+3] = a.w;
    }
    #pragma unroll
    for (int s = 1; s < KSPLIT; s++) {
        const float* bs = base + (size_t)s * MM * HH;
        #pragma unroll
        for (int j = 0; j < 8; j++) {
            float4 a = *(const float4*)(bs + j * 4);
            accv[4*j+0] += a.x; accv[4*j+1] += a.y;
            accv[4*j+2] += a.z; accv[4*j+3] += a.w;
        }
    }

    if (widx < 2) {
        ushort_t* out = (widx == 0) ? qo : ko_;
        #pragma unroll
        for (int j = 0; j < 4; j++) {
            short8 s_;
            #pragma unroll
            for (int e = 0; e < 8; e++) s_[e] = (short)f2bf(accv[j*8 + e]);
            *(short8*)&out[(size_t)(m0 + r_) * HH + h0 + j * 8] = s_;
        }
    } else {
        // transpose 64m x 128h tile via LDS -> vt[h][m]
        #pragma unroll
        for (int e = 0; e < 32; e++)
            T[(h0 + e) * 72 + r_] = f2bf(accv[e]);
        __syncthreads();
        const int h = tid >> 1, ms = (tid & 1) * 32;
        #pragma unroll
        for (int j = 0; j < 4; j++)
            *(short8*)&vto[(size_t)h * MM + m0 + ms + j * 8]
                = *(short8*)&T[h * 72 + ms + j * 8];
    }
}

// ---------------------------------------------------------------------------
// Kernel 3: MFMA flash attention partials (no-max streaming softmax, split-2).
// Qtile=32, Kchunk=64. Grid (64, 2, BB). bf16 q,k,vt in; fp32 partials out.
// ---------------------------------------------------------------------------
__global__ __launch_bounds__(256) void attn_mfma(
    const ushort_t* __restrict__ qb, const ushort_t* __restrict__ kbf,
    const ushort_t* __restrict__ vtb,
    float* __restrict__ OP, float* __restrict__ LP)
{
    const int b = blockIdx.z;
    const int s = blockIdx.y;
    const int t = 63 - (int)blockIdx.x;       // heavy tiles first
    const int tid  = threadIdx.x;
    const int lane = tid & 63, wave = tid >> 6;
    const int fr = lane & 15, quad = lane >> 4, ko = quad * 8;

    const int q0 = t * 32;
    const int C  = (t + 2) >> 1;              // chunks of 64 keys
    const int cs = (C + 1) >> 1;
    const int c0 = s ? cs : 0;
    const int c1 = s ? C  : cs;

    __shared__ __align__(16) ushort_t Qs[32 * 136];
    __shared__ __align__(16) ushort_t Ks[64 * 136];
    __shared__ __align__(16) ushort_t Vt[128 * 72];
    __shared__ __align__(16) ushort_t Ps[32 * 72];
    __shared__ float lred[2][32];

    // load Q tile (32 rows x 16 segs)
    for (int f = tid; f < 512; f += 256) {
        const int row = f >> 4, sg = f & 15;
        *(short8*)&Qs[row * 136 + sg * 8] =
            *(const short8*)(qb + (size_t)(b * TT + q0 + row) * HH + sg * 8);
    }

    const int rhS = (wave & 1) * 16, cqS = (wave >> 1) * 32;   // S partition
    const int rhO = (wave & 1) * 16, chO = (wave >> 1) * 64;   // O partition

    f32x4 oacc[4];
    #pragma unroll
    for (int i = 0; i < 4; i++) oacc[i] = (f32x4){0.f,0.f,0.f,0.f};
    float lacc[4] = {0.f, 0.f, 0.f, 0.f};

    for (int c = c0; c < c1; c++) {
        const int kb_ = c * 64;
        // stage K (64 x 16 segs)
        for (int f = tid; f < 1024; f += 256) {
            const int row = f >> 4, sg = f & 15;
            *(short8*)&Ks[row * 136 + sg * 8] =
                *(const short8*)(kbf + (size_t)(b * TT + kb_ + row) * HH + sg * 8);
        }
        // stage Vt (128 x 8 segs)
        for (int f = tid; f < 1024; f += 256) {
            const int h = f >> 3, sg = f & 7;
            *(short8*)&Vt[h * 72 + sg * 8] =
                *(const short8*)(vtb + (size_t)h * MM + b * TT + kb_ + sg * 8);
        }
        __syncthreads();

        // ---- QK: S[32x64], this wave: rows rhS..+16, cols cqS..+32 ----
        f32x4 sacc[2];
        sacc[0] = (f32x4){0.f,0.f,0.f,0.f};
        sacc[1] = (f32x4){0.f,0.f,0.f,0.f};
        #pragma unroll
        for (int kk = 0; kk < 128; kk += 32) {
            const short8 af = *(short8*)&Qs[(rhS + fr) * 136 + kk + ko];
            const short8 b0 = *(short8*)&Ks[(cqS + fr) * 136 + kk + ko];
            const short8 b1 = *(short8*)&Ks[(cqS + 16 + fr) * 136 + kk + ko];
            sacc[0] = __builtin_amdgcn_mfma_f32_16x16x32_bf16(af, b0, sacc[0], 0, 0, 0);
            sacc[1] = __builtin_amdgcn_mfma_f32_16x16x32_bf16(af, b1, sacc[1], 0, 0, 0);
        }

        // ---- epilogue: mask + exp -> Ps (bf16), accumulate l ----
        #pragma unroll
        for (int tl = 0; tl < 2; tl++)
            #pragma unroll
            for (int r = 0; r < 4; r++) {
                const int row = rhS + quad * 4 + r;
                const int col = cqS + tl * 16 + fr;
                const float p = ((kb_ + col) <= (q0 + row)) ? __expf(sacc[tl][r]) : 0.f;
                lacc[r] += p;
                Ps[row * 72 + col] = f2bf(p);
            }
        __syncthreads();

        // ---- PV: O[32x128] += P[32x64] * V; wave: rows rhO, cols chO..+64 ----
        #pragma unroll
        for (int ks = 0; ks < 64; ks += 32) {
            const short8 af = *(short8*)&Ps[(rhO + fr) * 72 + ks + ko];
            #pragma unroll
            for (int tl = 0; tl < 4; tl++) {
                const short8 bf_ = *(short8*)&Vt[(chO + tl * 16 + fr) * 72 + ks + ko];
                oacc[tl] = __builtin_amdgcn_mfma_f32_16x16x32_bf16(af, bf_, oacc[tl], 0, 0, 0);
            }
        }
        __syncthreads();
    }

    // ---- l reduction: sum over the 16 fr-lanes, combine col-halves ----
    #pragma unroll
    for (int r = 0; r < 4; r++) {
        float v = lacc[r];
        #pragma unroll
        for (int m = 1; m < 16; m <<= 1) v += __shfl_xor(v, m);
        lacc[r] = v;
    }
    if (fr == 0) {
        #pragma unroll
        for (int r = 0; r < 4; r++)
            lred[wave >> 1][rhS + quad * 4 + r] = lacc[r];
    }
    __syncthreads();
    const int pbase = ((b * 64 + t) * 2 + s);
    if (tid < 32) LP[(size_t)pbase * 32 + tid] = lred[0][tid] + lred[1][tid];

    // ---- write O partial ----
    #pragma unroll
    for (int tl = 0; tl < 4; tl++)
        #pragma unroll
        for (int r = 0; r < 4; r++) {
            const int row = rhO + quad * 4 + r;
            const int col = chO + tl * 16 + fr;
            OP[(size_t)pbase * 4096 + row * 128 + col] = oacc[tl][r];
        }
}

// ---------------------------------------------------------------------------
// Kernel 4: combine: out = (O0+O1)/(l0+l1). 262144 float4.
// ---------------------------------------------------------------------------
__global__ __launch_bounds__(256) void combine(
    const float* __restrict__ OP, const float* __restrict__ LP,
    float* __restrict__ out)
{
    const int gid = blockIdx.x * 256 + threadIdx.x;
    const int b = gid >> 16;
    const int rem = gid & 65535;
    const int qrow = rem >> 5, h4 = rem & 31;
    const int t = qrow >> 5, r = qrow & 31;
    const int base = (b * 64 + t) * 2;
    const float l = LP[(size_t)base * 32 + r] + LP[(size_t)(base + 1) * 32 + r];
    const float inv = 1.f / l;
    const float4 a = ((const float4*)OP)[(size_t)base * 1024 + r * 32 + h4];
    const float4 c = ((const float4*)OP)[(size_t)(base + 1) * 1024 + r * 32 + h4];
    float4 res;
    res.x = (a.x + c.x) * inv; res.y = (a.y + c.y) * inv;
    res.z = (a.z + c.z) * inv; res.w = (a.w + c.w) * inv;
    ((float4*)out)[gid] = res;
}

// ---------------------------------------------------------------------------
extern "C" void kernel_launch(void* const* d_in, const int* in_sizes, int n_in,
                              void* d_out, int out_size, void* d_ws, size_t ws_size,
                              hipStream_t stream) {
    const float* x  = (const float*)d_in[0];
    const float* pe = (const float*)d_in[1];
    const float* Wq = (const float*)d_in[2];
    const float* Wk = (const float*)d_in[3];
    const float* Wv = (const float*)d_in[4];
    float* out = (float*)d_out;

    ushort_t* qb  = (ushort_t*)d_ws;                 // [MM][HH] bf16   (2 MB)
    ushort_t* kbf = qb  + (size_t)MM * HH;           // [MM][HH] bf16   (2 MB)
    ushort_t* vtb = kbf + (size_t)MM * HH;           // [HH][MM] bf16   (2 MB)
    ushort_t* Wb  = vtb + (size_t)MM * HH;           // [3][128][4096]  (3 MB)
    float* Pp = (float*)(Wb + (size_t)3 * 128 * 4096); // [12][MM][HH] f32 (48 MB)
    float* OP = Pp;                                  // overlap: Pp dead before OP
    float* LP = OP + (size_t)512 * 4096;             // [512][32] f32

    wconv    <<<768, 256, 0, stream>>>(Wq, Wk, Wv, Wb);
    proj_mfma<<<dim3(64, 3, KSPLIT), 256, 0, stream>>>(x, pe, Wb, Pp);
    projcomb <<<dim3(128, 3), 256, 0, stream>>>(Pp, qb, kbf, vtb);
    attn_mfma<<<dim3(64, 2, BB), 256, 0, stream>>>(qb, kbf, vtb, OP, LP);
    combine  <<<1024, 256, 0, stream>>>(OP, LP, out);
}